// Round 2
// baseline (15701.898 us; speedup 1.0000x reference)
//
#include <hip/hip_runtime.h>
#include <hip/hip_bf16.h>

typedef __bf16 bf16x8 __attribute__((ext_vector_type(8)));
typedef float  floatx4 __attribute__((ext_vector_type(4)));

static constexpr int kT = 512, kH = 1024, k4H = 4096;

// ---------------------------------------------------------------------------
// Weight pack: wpk[np(256)][c(64)][lane(64)][j(8)] bf16  (MFMA B-fragment order)
//   n_local = lane&15 = hl*4 + g  (gates interleaved inside each 16-wide n-tile)
//   col_W   = g*1024 + np*4 + hl ;  np = cg*4 + nt  ->  hcol = cg*16 + nt*4 + hl
//   fused k = c*32 + (lane>>4)*8 + j   (c<32: Wx rows, c>=32: Wh rows)
// Also zeroes the 8192 flag counters (d_ws is re-poisoned before every launch).
// ---------------------------------------------------------------------------
__global__ void pack_w(const float* __restrict__ Wx, const float* __restrict__ Wh,
                       __bf16* __restrict__ wpk, int* __restrict__ cnt) {
  int idx = blockIdx.x * 256 + threadIdx.x;          // 1,048,576 threads
  if (idx < kT * 4 * 4) cnt[idx] = 0;                // 8192 flags
  int l  = idx & 63;
  int c  = (idx >> 6) & 63;
  int np = idx >> 12;                                // 0..255
  int nl = l & 15;
  int g  = nl & 3, hl = nl >> 2;
  int col = g * kH + np * 4 + hl;
  int kf  = (l >> 4) * 8;
  const float* src = (c < 32) ? Wx + (size_t)(c * 32 + kf) * k4H + col
                              : Wh + (size_t)((c - 32) * 32 + kf) * k4H + col;
  bf16x8 v;
#pragma unroll
  for (int j = 0; j < 8; ++j) v[j] = (__bf16)src[(size_t)j * k4H];
  *(bf16x8*)(wpk + (size_t)idx * 8) = v;
}

// ---------------------------------------------------------------------------
// x pack: xpk[t][mt(4)][c(32)][lane(64)][j(8)] bf16  (MFMA A-fragment order)
//   m = mt*16 + (lane&15),  k = c*32 + (lane>>4)*8 + j
// ---------------------------------------------------------------------------
__global__ void pack_x(const float* __restrict__ x, __bf16* __restrict__ xpk) {
  int idx = blockIdx.x * 256 + threadIdx.x;          // 4,194,304 threads
  int l  = idx & 63;
  int c  = (idx >> 6) & 31;
  int mt = (idx >> 11) & 3;
  int t  = idx >> 13;
  int m  = mt * 16 + (l & 15);
  int f  = c * 32 + (l >> 4) * 8;
  const float* src = x + ((size_t)m * kT + t) * 1024 + f;
  bf16x8 v;
#pragma unroll
  for (int j = 0; j < 8; ++j) v[j] = (__bf16)src[j];
  *(bf16x8*)(xpk + (size_t)idx * 8) = v;
}

// ---------------------------------------------------------------------------
// Persistent scan. REGULAR launch: 256 WGs x 512 thr (1 WG/CU -> all resident).
// WG = (cg 0..63: 16 h-cols, mq 0..3: 16 batch rows); XCD swizzle: blk&7 = mq*2+half.
// Wave w (0..7) owns fused-K slice w*256..w*256+255 (w<4: x@Wx, w>=4: h@Wh),
// weights resident in 128 VGPRs/lane. Per step: 32 MFMA/wave -> LDS reduce ->
// gates (threads 0..255, c-state in register) -> publish h (4-slot ring) + flag.
// Ring safety: same-mq WGs are never >1 step apart (flag needs all 16 producers).
// ---------------------------------------------------------------------------
__launch_bounds__(512, 2)
__global__ void lstm_scan(const __bf16* __restrict__ xpk, const __bf16* __restrict__ wpk,
                          const float* __restrict__ bias, __bf16* __restrict__ hpk,
                          int* __restrict__ cnt, float* __restrict__ out) {
  const int blk  = blockIdx.x;
  const int half = blk & 1;
  const int mq   = (blk >> 1) & 3;
  const int cg   = half * 32 + (blk >> 3);           // 0..63
  const int tid  = threadIdx.x;
  const int wave = tid >> 6;                         // 0..7
  const int lane = tid & 63;

  __shared__ __align__(16) float zbuf[8][16][68];    // 68: keeps float4 align, 2-way banks (free)

  // ---- persistent weight fragments: breg[ntile][chunk], chunk = wave*8+cc ----
  bf16x8 breg[4][8];
#pragma unroll
  for (int nt = 0; nt < 4; ++nt) {
    const __bf16* wsrc = wpk + (((size_t)(cg * 4 + nt) * 64 + wave * 8) * 64 + lane) * 8;
#pragma unroll
    for (int cc = 0; cc < 8; ++cc)
      breg[nt][cc] = *(const bf16x8*)(wsrc + (size_t)cc * 512);
  }

  // ---- gate-phase per-thread state (threads 0..255) ----
  const int gm   = (tid >> 4) & 15;                  // m within tile
  const int ghc  = tid & 15;                         // h-col within group
  const int m_g  = mq * 16 + gm;
  const int hcol = cg * 16 + ghc;
  const int gnt  = ghc >> 2, ghl = ghc & 3;
  float c_state  = 0.f;
  const float bi = bias[0 * kH + hcol], bf_ = bias[1 * kH + hcol];
  const float bg = bias[2 * kH + hcol], bo  = bias[3 * kH + hcol];
  const size_t slotE = 4 * 32 * 64 * 8;              // 65536 elems per ring slot
  const size_t hoff  = ((size_t)mq * 32 + (hcol >> 5)) * 512
                     + (size_t)(gm | (((hcol >> 3) & 3) << 4)) * 8 + (hcol & 7);
  const int myslice  = cg >> 4;

  floatx4 acc[4];
#pragma unroll
  for (int nt = 0; nt < 4; ++nt) acc[nt] = floatx4{0.f, 0.f, 0.f, 0.f};

  // ---- prologue: x-part of t=0 (h_{-1}=0 so h-waves contribute zero) ----
  if (wave < 4) {
    const __bf16* asrc = xpk + ((size_t)mq * 32 + wave * 8) * 512 + (size_t)lane * 8;
#pragma unroll
    for (int cc = 0; cc < 8; ++cc) {
      bf16x8 a = *(const bf16x8*)(asrc + (size_t)cc * 512);
#pragma unroll
      for (int nt = 0; nt < 4; ++nt)
        acc[nt] = __builtin_amdgcn_mfma_f32_16x16x32_bf16(a, breg[nt][cc], acc[nt], 0, 0, 0);
    }
  }

#pragma unroll 1
  for (int t = 0; t < kT; ++t) {
    __syncthreads();                                 // zbuf reads of t-1 complete
#pragma unroll
    for (int nt = 0; nt < 4; ++nt)
#pragma unroll
      for (int rr = 0; rr < 4; ++rr)
        zbuf[wave][(lane >> 4) * 4 + rr][nt * 16 + (lane & 15)] = acc[nt][rr];
    __syncthreads();

    if (tid < 256) {
      float zi = bi, zf = bf_, zg = bg, zo = bo;
      const float* zp = &zbuf[0][gm][gnt * 16 + ghl * 4];
#pragma unroll
      for (int w = 0; w < 8; ++w) {
        floatx4 zv = *(const floatx4*)(zp + (size_t)w * 16 * 68);
        zi += zv[0]; zf += zv[1]; zg += zv[2]; zo += zv[3];
      }
      float ig = 1.f / (1.f + __expf(-zi));
      float fg = 1.f / (1.f + __expf(-zf));
      float gg = 2.f / (1.f + __expf(-2.f * zg)) - 1.f;
      float og = 1.f / (1.f + __expf(-zo));
      c_state = fg * c_state + ig * gg;
      float tc = 2.f / (1.f + __expf(-2.f * c_state)) - 1.f;
      float h  = og * tc;
      out[((size_t)m_g * kT + t) * kH + hcol] = h;
      hpk[(size_t)(t & 3) * slotE + hoff] = (__bf16)h;
    }

    __syncthreads();                                 // drain h stores (vmcnt0 @ barrier)
    if (tid == 0) {
      __threadfence();                               // flush to agent scope (wbL2)
      atomicAdd(&cnt[(t * 4 + mq) * 4 + myslice], 1);
    }

    // ---- tail: partials for step t+1 ----
    if (t < kT - 1) {
#pragma unroll
      for (int nt = 0; nt < 4; ++nt) acc[nt] = floatx4{0.f, 0.f, 0.f, 0.f};
      if (wave < 4) {                                // x-part of t+1: runs ahead
        const __bf16* asrc = xpk + (((size_t)(t + 1) * 4 + mq) * 32 + wave * 8) * 512
                           + (size_t)lane * 8;
#pragma unroll
        for (int cc = 0; cc < 8; ++cc) {
          bf16x8 a = *(const bf16x8*)(asrc + (size_t)cc * 512);
#pragma unroll
          for (int nt = 0; nt < 4; ++nt)
            acc[nt] = __builtin_amdgcn_mfma_f32_16x16x32_bf16(a, breg[nt][cc], acc[nt], 0, 0, 0);
        }
      } else {                                       // h-part: wait for 16 slice producers
        const int s = wave - 4;
        const int* flag = &cnt[(t * 4 + mq) * 4 + s];
        int spins = 0;
        while (__hip_atomic_load(flag, __ATOMIC_RELAXED, __HIP_MEMORY_SCOPE_AGENT) < 16) {
          __builtin_amdgcn_s_sleep(2);
          if (++spins > (1 << 22)) break;            // bounded: fail loud, not hung
        }
        __threadfence();                             // acquire (invalidate stale L2)
        const __bf16* asrc = hpk + (size_t)(t & 3) * slotE
                           + ((size_t)mq * 32 + s * 8) * 512 + (size_t)lane * 8;
#pragma unroll
        for (int cc = 0; cc < 8; ++cc) {
          bf16x8 a = *(const bf16x8*)(asrc + (size_t)cc * 512);
#pragma unroll
          for (int nt = 0; nt < 4; ++nt)
            acc[nt] = __builtin_amdgcn_mfma_f32_16x16x32_bf16(a, breg[nt][cc], acc[nt], 0, 0, 0);
        }
      }
    }
  }
}

// ---------------------------------------------------------------------------
extern "C" void kernel_launch(void* const* d_in, const int* in_sizes, int n_in,
                              void* d_out, int out_size, void* d_ws, size_t ws_size,
                              hipStream_t stream) {
  const float* x  = (const float*)d_in[0];   // [64,512,1024]
  const float* Wx = (const float*)d_in[1];   // [1024,4096]
  const float* Wh = (const float*)d_in[2];   // [1024,4096]
  const float* b  = (const float*)d_in[3];   // [4096]
  float* out = (float*)d_out;

  char* ws = (char*)d_ws;
  int*    cnt = (int*)ws;                                   // 32 KB used
  __bf16* hpk = (__bf16*)(ws + (size_t)(1 << 16));          // 512 KB (4-slot ring)
  __bf16* wpk = (__bf16*)(ws + (size_t)(1 << 20));          // 16 MB
  __bf16* xpk = (__bf16*)(ws + (size_t)(17 << 20));         // 64 MB  (total 81 MB)
  (void)in_sizes; (void)n_in; (void)out_size; (void)ws_size;

  hipLaunchKernelGGL(pack_w, dim3(4096),  dim3(256), 0, stream, Wx, Wh, wpk, cnt);
  hipLaunchKernelGGL(pack_x, dim3(16384), dim3(256), 0, stream, x, xpk);
  hipLaunchKernelGGL(lstm_scan, dim3(256), dim3(512), 0, stream,
                     xpk, wpk, b, hpk, cnt, out);
}

// Round 3
// 3151.547 us; speedup vs baseline: 4.9823x; 4.9823x over previous
//
#include <hip/hip_runtime.h>
#include <hip/hip_bf16.h>

typedef __bf16 bf16x8 __attribute__((ext_vector_type(8)));
typedef float  floatx4 __attribute__((ext_vector_type(4)));

static constexpr int kT = 512, kH = 1024, k4H = 4096;
static constexpr int kFlagStride = 16;               // ints; 64B line per flag

// ---------------------------------------------------------------------------
// Weight pack: wpk[np(256)][c(64)][lane(64)][j(8)] bf16  (MFMA B-fragment order)
//   n_local = lane&15 = hl*4 + g  (gates interleaved inside each 16-wide n-tile)
//   col_W   = g*1024 + np*4 + hl ;  np = cg*4 + nt  ->  hcol = cg*16 + nt*4 + hl
//   fused k = c*32 + (lane>>4)*8 + j   (c<32: Wx rows, c>=32: Wh rows)
// Also zeroes the flag lines (d_ws is re-poisoned before every launch).
// ---------------------------------------------------------------------------
__global__ void pack_w(const float* __restrict__ Wx, const float* __restrict__ Wh,
                       __bf16* __restrict__ wpk, int* __restrict__ cnt) {
  int idx = blockIdx.x * 256 + threadIdx.x;          // 1,048,576 threads
  if (idx < kT * 4 * 4 * kFlagStride) cnt[idx] = 0;  // 512 KB of flags
  int l  = idx & 63;
  int c  = (idx >> 6) & 63;
  int np = idx >> 12;                                // 0..255
  int nl = l & 15;
  int g  = nl & 3, hl = nl >> 2;
  int col = g * kH + np * 4 + hl;
  int kf  = (l >> 4) * 8;
  const float* src = (c < 32) ? Wx + (size_t)(c * 32 + kf) * k4H + col
                              : Wh + (size_t)((c - 32) * 32 + kf) * k4H + col;
  bf16x8 v;
#pragma unroll
  for (int j = 0; j < 8; ++j) v[j] = (__bf16)src[(size_t)j * k4H];
  *(bf16x8*)(wpk + (size_t)idx * 8) = v;
}

// ---------------------------------------------------------------------------
// x pack: xpk[t][mt(4)][c(32)][lane(64)][j(8)] bf16  (MFMA A-fragment order)
//   m = mt*16 + (lane&15),  k = c*32 + (lane>>4)*8 + j
// ---------------------------------------------------------------------------
__global__ void pack_x(const float* __restrict__ x, __bf16* __restrict__ xpk) {
  int idx = blockIdx.x * 256 + threadIdx.x;          // 4,194,304 threads
  int l  = idx & 63;
  int c  = (idx >> 6) & 31;
  int mt = (idx >> 11) & 3;
  int t  = idx >> 13;
  int m  = mt * 16 + (l & 15);
  int f  = c * 32 + (l >> 4) * 8;
  const float* src = x + ((size_t)m * kT + t) * 1024 + f;
  bf16x8 v;
#pragma unroll
  for (int j = 0; j < 8; ++j) v[j] = (__bf16)src[j];
  *(bf16x8*)(xpk + (size_t)idx * 8) = v;
}

// ---------------------------------------------------------------------------
// Persistent scan, regular launch: 256 WGs x 512 thr (1 WG/CU, all resident).
// WG = (cg 0..63, mq 0..3); XCD swizzle: blk&7 = mq*2+half (chain stays on 2 XCDs).
// Wave w owns fused-K slice w*256.. (w<4: x@Wx, w>=4: h@Wh); weights pinned in
// 128 VGPRs/lane via asm. h exchange is FENCE-FREE: write-through sc1 stores
// (visible once vmcnt drains at __syncthreads) + sc1 loads (bypass stale L2);
// flag = device-scope atomicAdd after the barrier. Local L2 stays warm.
// ---------------------------------------------------------------------------
__launch_bounds__(512, 2)
__global__ void lstm_scan(const __bf16* __restrict__ xpk, const __bf16* __restrict__ wpk,
                          const float* __restrict__ bias, __bf16* __restrict__ hpk,
                          int* __restrict__ cnt, float* __restrict__ out) {
  const int blk  = blockIdx.x;
  const int half = blk & 1;
  const int mq   = (blk >> 1) & 3;
  const int cg   = half * 32 + (blk >> 3);           // 0..63
  const int tid  = threadIdx.x;
  const int wave = tid >> 6;                         // 0..7
  const int lane = tid & 63;

  __shared__ __align__(16) float zbuf[8][16][68];    // float4-aligned, 2-way banks (free)

  // ---- persistent weight fragments: breg[ntile][chunk], chunk = wave*8+cc ----
  bf16x8 breg[4][8];
#pragma unroll
  for (int nt = 0; nt < 4; ++nt) {
    const __bf16* wsrc = wpk + (((size_t)(cg * 4 + nt) * 64 + wave * 8) * 64 + lane) * 8;
#pragma unroll
    for (int cc = 0; cc < 8; ++cc)
      breg[nt][cc] = *(const bf16x8*)(wsrc + (size_t)cc * 512);
  }
  // Pin in VGPRs: asm may "modify" the value, so reloading from wpk is illegal.
#pragma unroll
  for (int nt = 0; nt < 4; ++nt)
#pragma unroll
    for (int cc = 0; cc < 8; ++cc)
      asm volatile("" : "+v"(breg[nt][cc]));

  // ---- gate-phase per-thread state (threads 0..255) ----
  const int gm   = (tid >> 4) & 15;
  const int ghc  = tid & 15;
  const int m_g  = mq * 16 + gm;
  const int hcol = cg * 16 + ghc;
  const int gnt  = ghc >> 2, ghl = ghc & 3;
  float c_state  = 0.f;
  const float bi = bias[0 * kH + hcol], bf_ = bias[1 * kH + hcol];
  const float bg = bias[2 * kH + hcol], bo  = bias[3 * kH + hcol];
  const size_t slotE = 4 * 32 * 64 * 8;              // 65536 elems per ring slot
  const size_t hoff  = ((size_t)mq * 32 + (hcol >> 5)) * 512
                     + (size_t)(gm | (((hcol >> 3) & 3) << 4)) * 8 + (hcol & 7);
  const int myslice  = cg >> 4;

  floatx4 acc[4];
#pragma unroll
  for (int nt = 0; nt < 4; ++nt) acc[nt] = floatx4{0.f, 0.f, 0.f, 0.f};

  // ---- prologue: x-part of t=0 (h_{-1}=0 so h-waves contribute zero) ----
  if (wave < 4) {
    const __bf16* asrc = xpk + ((size_t)mq * 32 + wave * 8) * 512 + (size_t)lane * 8;
#pragma unroll
    for (int cc = 0; cc < 8; ++cc) {
      bf16x8 a = *(const bf16x8*)(asrc + (size_t)cc * 512);
#pragma unroll
      for (int nt = 0; nt < 4; ++nt)
        acc[nt] = __builtin_amdgcn_mfma_f32_16x16x32_bf16(a, breg[nt][cc], acc[nt], 0, 0, 0);
    }
  }

#pragma unroll 1
  for (int t = 0; t < kT; ++t) {
    __syncthreads();                                 // zbuf reads of t-1 complete
#pragma unroll
    for (int nt = 0; nt < 4; ++nt)
#pragma unroll
      for (int rr = 0; rr < 4; ++rr)
        zbuf[wave][(lane >> 4) * 4 + rr][nt * 16 + (lane & 15)] = acc[nt][rr];
    __syncthreads();

    if (tid < 256) {
      float zi = bi, zf = bf_, zg = bg, zo = bo;
      const float* zp = &zbuf[0][gm][gnt * 16 + ghl * 4];
#pragma unroll
      for (int w = 0; w < 8; ++w) {
        floatx4 zv = *(const floatx4*)(zp + (size_t)w * 16 * 68);
        zi += zv[0]; zf += zv[1]; zg += zv[2]; zo += zv[3];
      }
      float ig = 1.f / (1.f + __expf(-zi));
      float fg = 1.f / (1.f + __expf(-zf));
      float gg = 2.f / (1.f + __expf(-2.f * zg)) - 1.f;
      float og = 1.f / (1.f + __expf(-zo));
      c_state = fg * c_state + ig * gg;
      float tc = 2.f / (1.f + __expf(-2.f * c_state)) - 1.f;
      float h  = og * tc;
      out[((size_t)m_g * kT + t) * kH + hcol] = h;
      // Write-through (sc1) store: visible device-wide once vmcnt retires.
      __bf16 hb = (__bf16)h;
      unsigned short hbits;
      __builtin_memcpy(&hbits, &hb, 2);
      __hip_atomic_store((unsigned short*)(hpk + (size_t)(t & 3) * slotE + hoff),
                         hbits, __ATOMIC_RELAXED, __HIP_MEMORY_SCOPE_AGENT);
    }

    __syncthreads();                                 // drains vmcnt -> h globally visible
    if (tid == 0)
      atomicAdd(&cnt[((t * 4 + mq) * 4 + myslice) * kFlagStride], 1);

    // ---- tail: partials for step t+1 ----
    if (t < kT - 1) {
#pragma unroll
      for (int nt = 0; nt < 4; ++nt) acc[nt] = floatx4{0.f, 0.f, 0.f, 0.f};
      if (wave < 4) {                                // x-part of t+1: runs ahead
        const __bf16* asrc = xpk + (((size_t)(t + 1) * 4 + mq) * 32 + wave * 8) * 512
                           + (size_t)lane * 8;
#pragma unroll
        for (int cc = 0; cc < 8; ++cc) {
          bf16x8 a = *(const bf16x8*)(asrc + (size_t)cc * 512);
#pragma unroll
          for (int nt = 0; nt < 4; ++nt)
            acc[nt] = __builtin_amdgcn_mfma_f32_16x16x32_bf16(a, breg[nt][cc], acc[nt], 0, 0, 0);
        }
      } else {                                       // h-part: wait for 16 slice producers
        const int s = wave - 4;
        const int* flag = &cnt[((t * 4 + mq) * 4 + s) * kFlagStride];
        int spins = 0;
        while (__hip_atomic_load(flag, __ATOMIC_RELAXED, __HIP_MEMORY_SCOPE_AGENT) < 16) {
          __builtin_amdgcn_s_sleep(1);
          if (++spins > (1 << 22)) break;            // bounded: fail loud, not hung
        }
        asm volatile("" ::: "memory");               // no hoisting h loads above the poll
        const __bf16* asrc = hpk + (size_t)(t & 3) * slotE
                           + ((size_t)mq * 32 + s * 8) * 512 + (size_t)lane * 8;
#pragma unroll
        for (int cc = 0; cc < 8; ++cc) {
          // sc1 loads: read at the coherence point (local L2 may hold stale ring data)
          const unsigned long long* p = (const unsigned long long*)(asrc + (size_t)cc * 512);
          union { unsigned long long q[2]; bf16x8 v; } u;
          u.q[0] = __hip_atomic_load(p,     __ATOMIC_RELAXED, __HIP_MEMORY_SCOPE_AGENT);
          u.q[1] = __hip_atomic_load(p + 1, __ATOMIC_RELAXED, __HIP_MEMORY_SCOPE_AGENT);
#pragma unroll
          for (int nt = 0; nt < 4; ++nt)
            acc[nt] = __builtin_amdgcn_mfma_f32_16x16x32_bf16(u.v, breg[nt][cc], acc[nt], 0, 0, 0);
        }
      }
    }
  }
}

// ---------------------------------------------------------------------------
extern "C" void kernel_launch(void* const* d_in, const int* in_sizes, int n_in,
                              void* d_out, int out_size, void* d_ws, size_t ws_size,
                              hipStream_t stream) {
  const float* x  = (const float*)d_in[0];   // [64,512,1024]
  const float* Wx = (const float*)d_in[1];   // [1024,4096]
  const float* Wh = (const float*)d_in[2];   // [1024,4096]
  const float* b  = (const float*)d_in[3];   // [4096]
  float* out = (float*)d_out;

  char* ws = (char*)d_ws;
  int*    cnt = (int*)ws;                                   // 512 KB flag lines
  __bf16* hpk = (__bf16*)(ws + (size_t)(1 << 19));          // 512 KB (4-slot ring)
  __bf16* wpk = (__bf16*)(ws + (size_t)(1 << 20));          // 16 MB
  __bf16* xpk = (__bf16*)(ws + (size_t)(17 << 20));         // 64 MB  (total 81 MB)
  (void)in_sizes; (void)n_in; (void)out_size; (void)ws_size;

  hipLaunchKernelGGL(pack_w, dim3(4096),  dim3(256), 0, stream, Wx, Wh, wpk, cnt);
  hipLaunchKernelGGL(pack_x, dim3(16384), dim3(256), 0, stream, x, xpk);
  hipLaunchKernelGGL(lstm_scan, dim3(256), dim3(512), 0, stream,
                     xpk, wpk, b, hpk, cnt, out);
}

// Round 4
// 2345.769 us; speedup vs baseline: 6.6937x; 1.3435x over previous
//
#include <hip/hip_runtime.h>
#include <hip/hip_bf16.h>
#include <stdint.h>

typedef __bf16 bf16x8 __attribute__((ext_vector_type(8)));
typedef float  floatx4 __attribute__((ext_vector_type(4)));

static constexpr int kT = 512, kH = 1024, k4H = 4096;

// ---------------------------------------------------------------------------
// Weight pack: wpk[np(256)][c(64)][lane(64)][j(8)] bf16  (MFMA B-fragment order)
//   n_local = lane&15 = hl*4 + g  (gates interleaved inside each 16-wide n-tile)
//   col_W   = g*1024 + np*4 + hl ;  np = cg*4 + nt  ->  hcol = cg*16 + nt*4 + hl
//   fused k = c*32 + (lane>>4)*8 + j   (c<32: Wx rows, c>=32: Wh rows)
// ---------------------------------------------------------------------------
__global__ void pack_w(const float* __restrict__ Wx, const float* __restrict__ Wh,
                       __bf16* __restrict__ wpk) {
  int idx = blockIdx.x * 256 + threadIdx.x;          // 1,048,576 threads
  int l  = idx & 63;
  int c  = (idx >> 6) & 63;
  int np = idx >> 12;                                // 0..255
  int nl = l & 15;
  int g  = nl & 3, hl = nl >> 2;
  int col = g * kH + np * 4 + hl;
  int kf  = (l >> 4) * 8;
  const float* src = (c < 32) ? Wx + (size_t)(c * 32 + kf) * k4H + col
                              : Wh + (size_t)((c - 32) * 32 + kf) * k4H + col;
  bf16x8 v;
#pragma unroll
  for (int j = 0; j < 8; ++j) v[j] = (__bf16)src[(size_t)j * k4H];
  *(bf16x8*)(wpk + (size_t)idx * 8) = v;
}

// ---------------------------------------------------------------------------
// x pack: xpk[t][mt(4)][c(32)][lane(64)][j(8)] bf16  (MFMA A-fragment order)
//   m = mt*16 + (lane&15),  k = c*32 + (lane>>4)*8 + j
// ---------------------------------------------------------------------------
__global__ void pack_x(const float* __restrict__ x, __bf16* __restrict__ xpk) {
  int idx = blockIdx.x * 256 + threadIdx.x;          // 4,194,304 threads
  int l  = idx & 63;
  int c  = (idx >> 6) & 31;
  int mt = (idx >> 11) & 3;
  int t  = idx >> 13;
  int m  = mt * 16 + (l & 15);
  int f  = c * 32 + (l >> 4) * 8;
  const float* src = x + ((size_t)m * kT + t) * 1024 + f;
  bf16x8 v;
#pragma unroll
  for (int j = 0; j < 8; ++j) v[j] = (__bf16)src[j];
  *(bf16x8*)(xpk + (size_t)idx * 8) = v;
}

// ---------------------------------------------------------------------------
// Persistent scan, 256 WGs x 512 thr (1 WG/CU). WG = (cg 0..63, mq 0..3).
// h exchange: TAGGED words (t<<16 | bf16 h) in a 4-slot ring; the data is its
// own flag (per-dword store atomicity). No atomics, no flags, no fences:
// consumers speculatively load and retry until all tags == t. Ring safety:
// publishing t+2 requires having observed all tags t+1, which implies every
// WG consumed slot t&3 already (depth-4 ring = 2 extra steps of margin).
// tg layout (dwords): [slot(4)][mq(4)][hg = hcol>>3 (128)][gm(16)][j = hcol&7 (8)]
// ---------------------------------------------------------------------------
__launch_bounds__(512, 2)
__global__ void lstm_scan(const __bf16* __restrict__ xpk, const __bf16* __restrict__ wpk,
                          const float* __restrict__ bias, uint32_t* __restrict__ tg,
                          float* __restrict__ out) {
  const int blk  = blockIdx.x;
  const int half = blk & 1;
  const int mq   = (blk >> 1) & 3;
  const int cg   = half * 32 + (blk >> 3);           // 0..63
  const int tid  = threadIdx.x;
  const int wave = tid >> 6;                         // 0..7
  const int lane = tid & 63;

  __shared__ __align__(16) float zbuf[8][16][68];

  // ---- persistent weight fragments: breg[ntile][chunk], chunk = wave*8+cc ----
  bf16x8 breg[4][8];
#pragma unroll
  for (int nt = 0; nt < 4; ++nt) {
    const __bf16* wsrc = wpk + (((size_t)(cg * 4 + nt) * 64 + wave * 8) * 64 + lane) * 8;
#pragma unroll
    for (int cc = 0; cc < 8; ++cc)
      breg[nt][cc] = *(const bf16x8*)(wsrc + (size_t)cc * 512);
  }
#pragma unroll
  for (int nt = 0; nt < 4; ++nt)
#pragma unroll
    for (int cc = 0; cc < 8; ++cc)
      asm volatile("" : "+v"(breg[nt][cc]));         // pin: no remat from memory

  // ---- gate-phase per-thread state (threads 0..255) ----
  const int gm   = (tid >> 4) & 15;
  const int ghc  = tid & 15;
  const int m_g  = mq * 16 + gm;
  const int hcol = cg * 16 + ghc;
  const int gnt  = ghc >> 2, ghl = ghc & 3;
  float c_state  = 0.f;
  const float bi = bias[0 * kH + hcol], bf_ = bias[1 * kH + hcol];
  const float bg = bias[2 * kH + hcol], bo  = bias[3 * kH + hcol];
  // tagged-word index (dwords), minus the slot term (slot adds slot*65536)
  const int tgoff = ((mq * 128 + cg * 2 + (ghc >> 3)) * 16 + gm) * 8 + (ghc & 7);

  floatx4 acc[4];
#pragma unroll
  for (int nt = 0; nt < 4; ++nt) acc[nt] = floatx4{0.f, 0.f, 0.f, 0.f};

  // ---- prologue: x-part of t=0 (h_{-1}=0 so h-waves contribute zero) ----
  if (wave < 4) {
    const __bf16* asrc = xpk + ((size_t)mq * 32 + wave * 8) * 512 + (size_t)lane * 8;
#pragma unroll
    for (int cc = 0; cc < 8; ++cc) {
      bf16x8 a = *(const bf16x8*)(asrc + (size_t)cc * 512);
#pragma unroll
      for (int nt = 0; nt < 4; ++nt)
        acc[nt] = __builtin_amdgcn_mfma_f32_16x16x32_bf16(a, breg[nt][cc], acc[nt], 0, 0, 0);
    }
  }

#pragma unroll 1
  for (int t = 0; t < kT; ++t) {
    // publish partials to LDS (all zbuf readers of step t-1 passed B3 already)
#pragma unroll
    for (int nt = 0; nt < 4; ++nt)
#pragma unroll
      for (int rr = 0; rr < 4; ++rr)
        zbuf[wave][(lane >> 4) * 4 + rr][nt * 16 + (lane & 15)] = acc[nt][rr];
    __syncthreads();                                 // B2: zbuf complete

    if (tid < 256) {
      float zi = bi, zf = bf_, zg = bg, zo = bo;
      const float* zp = &zbuf[0][gm][gnt * 16 + ghl * 4];
#pragma unroll
      for (int w = 0; w < 8; ++w) {
        floatx4 zv = *(const floatx4*)(zp + (size_t)w * 16 * 68);
        zi += zv[0]; zf += zv[1]; zg += zv[2]; zo += zv[3];
      }
      float ig = 1.f / (1.f + __expf(-zi));
      float fg = 1.f / (1.f + __expf(-zf));
      float gg = 2.f / (1.f + __expf(-2.f * zg)) - 1.f;
      float og = 1.f / (1.f + __expf(-zo));
      c_state = fg * c_state + ig * gg;
      float tc = 2.f / (1.f + __expf(-2.f * c_state)) - 1.f;
      float h  = og * tc;
      // tagged publish FIRST (critical path), then the nt out-store
      __bf16 hb16 = (__bf16)h;
      uint16_t hbits;
      __builtin_memcpy(&hbits, &hb16, 2);
      uint32_t tagged = ((uint32_t)t << 16) | (uint32_t)hbits;
      __hip_atomic_store(&tg[(size_t)(t & 3) * 65536 + tgoff], tagged,
                         __ATOMIC_RELAXED, __HIP_MEMORY_SCOPE_AGENT);
      __builtin_nontemporal_store(h, &out[((size_t)m_g * kT + t) * kH + hcol]);
    }
    __syncthreads();                                 // B3: local publishes issued

    // ---- tail: partials for step t+1 ----
    if (t < kT - 1) {
#pragma unroll
      for (int nt = 0; nt < 4; ++nt) acc[nt] = floatx4{0.f, 0.f, 0.f, 0.f};
      if (wave < 4) {                                // x-part of t+1: runs ahead
        const __bf16* asrc = xpk + (((size_t)(t + 1) * 4 + mq) * 32 + wave * 8) * 512
                           + (size_t)lane * 8;
#pragma unroll
        for (int cc = 0; cc < 8; ++cc) {
          bf16x8 a = __builtin_nontemporal_load((const bf16x8*)(asrc + (size_t)cc * 512));
#pragma unroll
          for (int nt = 0; nt < 4; ++nt)
            acc[nt] = __builtin_amdgcn_mfma_f32_16x16x32_bf16(a, breg[nt][cc], acc[nt], 0, 0, 0);
        }
      } else {                                       // h-part: tagged speculative loads
        const int s = wave - 4;
        const uint64_t tt64 = ((uint64_t)(uint32_t)t << 16) | ((uint64_t)(uint32_t)t << 48);
        const uint64_t* hb = (const uint64_t*)tg + (size_t)(t & 3) * 32768
                           + ((size_t)(mq * 128 + s * 32 + (lane >> 4)) * 16 + (lane & 15)) * 4;
#pragma unroll
        for (int g2 = 0; g2 < 2; ++g2) {             // 2 rounds of 4 chunks (VGPR budget)
          uint64_t w[4][4];
          int guard = 0;
          for (;;) {
#pragma unroll
            for (int c2 = 0; c2 < 4; ++c2)
#pragma unroll
              for (int jj = 0; jj < 4; ++jj)
                w[c2][jj] = __hip_atomic_load(hb + (size_t)(g2 * 4 + c2) * 256 + jj,
                                              __ATOMIC_RELAXED, __HIP_MEMORY_SCOPE_AGENT);
            uint64_t bad = 0;
#pragma unroll
            for (int c2 = 0; c2 < 4; ++c2)
#pragma unroll
              for (int jj = 0; jj < 4; ++jj)
                bad |= (w[c2][jj] ^ tt64);
            bad &= 0xFFFF0000FFFF0000ull;
            if (!__any(bad != 0)) break;             // all 32 tags == t
            if (++guard > (1 << 20)) break;          // fail loud, not hung
          }
#pragma unroll
          for (int c2 = 0; c2 < 4; ++c2) {
            uint32_t d0 = (uint32_t)w[c2][0], d1 = (uint32_t)(w[c2][0] >> 32);
            uint32_t d2 = (uint32_t)w[c2][1], d3 = (uint32_t)(w[c2][1] >> 32);
            uint32_t d4 = (uint32_t)w[c2][2], d5 = (uint32_t)(w[c2][2] >> 32);
            uint32_t d6 = (uint32_t)w[c2][3], d7 = (uint32_t)(w[c2][3] >> 32);
            union { uint32_t u[4]; bf16x8 v; } uu;
            uu.u[0] = __builtin_amdgcn_perm(d1, d0, 0x05040100);  // (h1<<16)|h0
            uu.u[1] = __builtin_amdgcn_perm(d3, d2, 0x05040100);
            uu.u[2] = __builtin_amdgcn_perm(d5, d4, 0x05040100);
            uu.u[3] = __builtin_amdgcn_perm(d7, d6, 0x05040100);
#pragma unroll
            for (int nt = 0; nt < 4; ++nt)
              acc[nt] = __builtin_amdgcn_mfma_f32_16x16x32_bf16(uu.v, breg[nt][g2 * 4 + c2],
                                                                acc[nt], 0, 0, 0);
          }
        }
      }
    }
  }
}

// ---------------------------------------------------------------------------
extern "C" void kernel_launch(void* const* d_in, const int* in_sizes, int n_in,
                              void* d_out, int out_size, void* d_ws, size_t ws_size,
                              hipStream_t stream) {
  const float* x  = (const float*)d_in[0];   // [64,512,1024]
  const float* Wx = (const float*)d_in[1];   // [1024,4096]
  const float* Wh = (const float*)d_in[2];   // [1024,4096]
  const float* b  = (const float*)d_in[3];   // [4096]
  float* out = (float*)d_out;

  char* ws = (char*)d_ws;
  uint32_t* tgb = (uint32_t*)ws;                            // 1 MB tagged h ring
  __bf16*   wpk = (__bf16*)(ws + ((size_t)1 << 20));        // 16 MB
  __bf16*   xpk = (__bf16*)(ws + ((size_t)17 << 20));       // 64 MB  (total 81 MB)
  (void)in_sizes; (void)n_in; (void)out_size; (void)ws_size;

  hipLaunchKernelGGL(pack_w, dim3(4096),  dim3(256), 0, stream, Wx, Wh, wpk);
  hipLaunchKernelGGL(pack_x, dim3(16384), dim3(256), 0, stream, x, xpk);
  hipLaunchKernelGGL(lstm_scan, dim3(256), dim3(512), 0, stream,
                     xpk, wpk, b, tgb, out);
}

// Round 5
// 1882.344 us; speedup vs baseline: 8.3417x; 1.2462x over previous
//
#include <hip/hip_runtime.h>
#include <hip/hip_bf16.h>
#include <stdint.h>

typedef __bf16 bf16x8 __attribute__((ext_vector_type(8)));
typedef float  floatx4 __attribute__((ext_vector_type(4)));

static constexpr int kT = 512, kH = 1024, k4H = 4096;

// ---------------------------------------------------------------------------
// Weight pack: wpk[np(256)][c(64)][lane(64)][j(8)] bf16  (MFMA B-fragment order)
//   n_local = lane&15 = hl*4 + g  (gates interleaved inside each 16-wide n-tile)
//   col_W   = g*1024 + np*4 + hl ;  np = cg*4 + nt  ->  hcol = cg*16 + nt*4 + hl
//   fused k = c*32 + (lane>>4)*8 + j   (c<32: Wx rows, c>=32: Wh rows)
// ---------------------------------------------------------------------------
__global__ void pack_w(const float* __restrict__ Wx, const float* __restrict__ Wh,
                       __bf16* __restrict__ wpk) {
  int idx = blockIdx.x * 256 + threadIdx.x;          // 1,048,576 threads
  int l  = idx & 63;
  int c  = (idx >> 6) & 63;
  int np = idx >> 12;                                // 0..255
  int nl = l & 15;
  int g  = nl & 3, hl = nl >> 2;
  int col = g * kH + np * 4 + hl;
  int kf  = (l >> 4) * 8;
  const float* src = (c < 32) ? Wx + (size_t)(c * 32 + kf) * k4H + col
                              : Wh + (size_t)((c - 32) * 32 + kf) * k4H + col;
  bf16x8 v;
#pragma unroll
  for (int j = 0; j < 8; ++j) v[j] = (__bf16)src[(size_t)j * k4H];
  *(bf16x8*)(wpk + (size_t)idx * 8) = v;
}

// ---------------------------------------------------------------------------
// x pack: xpk[t][mt(4)][c(32)][lane(64)][j(8)] bf16  (MFMA A-fragment order)
//   m = mt*16 + (lane&15),  k = c*32 + (lane>>4)*8 + j
// ---------------------------------------------------------------------------
__global__ void pack_x(const float* __restrict__ x, __bf16* __restrict__ xpk) {
  int idx = blockIdx.x * 256 + threadIdx.x;          // 4,194,304 threads
  int l  = idx & 63;
  int c  = (idx >> 6) & 31;
  int mt = (idx >> 11) & 3;
  int t  = idx >> 13;
  int m  = mt * 16 + (l & 15);
  int f  = c * 32 + (l >> 4) * 8;
  const float4* src = (const float4*)(x + ((size_t)m * kT + t) * 1024 + f);
  float4 r0 = src[0], r1 = src[1];
  bf16x8 v;
  v[0] = (__bf16)r0.x; v[1] = (__bf16)r0.y; v[2] = (__bf16)r0.z; v[3] = (__bf16)r0.w;
  v[4] = (__bf16)r1.x; v[5] = (__bf16)r1.y; v[6] = (__bf16)r1.z; v[7] = (__bf16)r1.w;
  *(bf16x8*)(xpk + (size_t)idx * 8) = v;
}

// ---------------------------------------------------------------------------
// Persistent scan, 256 WGs x 512 thr (1 WG/CU). WG = (cg 0..63, mq 0..3).
// h exchange, two structures:
//   DATA: hd ring (4 slots), packed 2xbf16/dword, written sc1 by gate threads,
//         read ONCE per step by consumers (16 dwordx2 sc1 loads, no retry).
//   DETECT: per-producer sentinel dwords, 16 per 64B line = one line per
//         (mq, slice). Producer writes sent[..][cg&15] = t AFTER B3 (barrier's
//         vmcnt(0) drain orders it after the h stores). Consumer polls ONE
//         line per iteration + s_sleep throttle -> no fabric storm.
// No atomively-RMW'd flags anywhere; sentinel value==t is poison/init-safe
// (ring mod 8). Data-ring overwrite margin: 3 steps (proof: publishing t+4
// requires sentinels t+3, which requires every WG consumed slot t&3).
// hd layout (dwords): [slot(4)][mq(4)][hg=hcol>>3 (128)][gm(16)][d=(hcol&7)/2 (4)]
// ---------------------------------------------------------------------------
__launch_bounds__(512, 2)
__global__ void lstm_scan(const __bf16* __restrict__ xpk, const __bf16* __restrict__ wpk,
                          const float* __restrict__ bias, uint32_t* __restrict__ hd,
                          int* __restrict__ sent, float* __restrict__ out) {
  const int blk  = blockIdx.x;
  const int half = blk & 1;
  const int mq   = (blk >> 1) & 3;
  const int cg   = half * 32 + (blk >> 3);           // 0..63
  const int tid  = threadIdx.x;
  const int wave = tid >> 6;                         // 0..7
  const int lane = tid & 63;

  __shared__ __align__(16) float zbuf[8][16][68];

  // ---- persistent weight fragments: breg[ntile][chunk], chunk = wave*8+cc ----
  bf16x8 breg[4][8];
#pragma unroll
  for (int nt = 0; nt < 4; ++nt) {
    const __bf16* wsrc = wpk + (((size_t)(cg * 4 + nt) * 64 + wave * 8) * 64 + lane) * 8;
#pragma unroll
    for (int cc = 0; cc < 8; ++cc)
      breg[nt][cc] = *(const bf16x8*)(wsrc + (size_t)cc * 512);
  }
#pragma unroll
  for (int nt = 0; nt < 4; ++nt)
#pragma unroll
    for (int cc = 0; cc < 8; ++cc)
      asm volatile("" : "+v"(breg[nt][cc]));         // pin: no remat from memory

  // ---- gate-phase per-thread state (threads 0..255) ----
  const int gm   = (tid >> 4) & 15;
  const int ghc  = tid & 15;
  const int m_g  = mq * 16 + gm;
  const int hcol = cg * 16 + ghc;
  const int gnt  = ghc >> 2, ghl = ghc & 3;
  float c_state  = 0.f;
  const float bi = bias[0 * kH + hcol], bf_ = bias[1 * kH + hcol];
  const float bg = bias[2 * kH + hcol], bo  = bias[3 * kH + hcol];
  // packed-h dword index (minus slot term slot*32768)
  const int hdoff = ((mq * 128 + cg * 2 + (ghc >> 3)) * 16 + gm) * 4 + ((ghc & 7) >> 1);

  floatx4 acc[4];
#pragma unroll
  for (int nt = 0; nt < 4; ++nt) acc[nt] = floatx4{0.f, 0.f, 0.f, 0.f};

  // ---- prologue: x-part of t=0 (h_{-1}=0 so h-waves contribute zero) ----
  if (wave < 4) {
    const __bf16* asrc = xpk + ((size_t)mq * 32 + wave * 8) * 512 + (size_t)lane * 8;
#pragma unroll
    for (int cc = 0; cc < 8; ++cc) {
      bf16x8 a = *(const bf16x8*)(asrc + (size_t)cc * 512);
#pragma unroll
      for (int nt = 0; nt < 4; ++nt)
        acc[nt] = __builtin_amdgcn_mfma_f32_16x16x32_bf16(a, breg[nt][cc], acc[nt], 0, 0, 0);
    }
  }

#pragma unroll 1
  for (int t = 0; t < kT; ++t) {
    // publish partials to LDS (all zbuf readers of step t-1 passed B3 already)
#pragma unroll
    for (int nt = 0; nt < 4; ++nt)
#pragma unroll
      for (int rr = 0; rr < 4; ++rr)
        zbuf[wave][(lane >> 4) * 4 + rr][nt * 16 + (lane & 15)] = acc[nt][rr];
    __syncthreads();                                 // B2: zbuf complete

    if (tid < 256) {
      float zi = bi, zf = bf_, zg = bg, zo = bo;
      const float* zp = &zbuf[0][gm][gnt * 16 + ghl * 4];
#pragma unroll
      for (int w = 0; w < 8; ++w) {
        floatx4 zv = *(const floatx4*)(zp + (size_t)w * 16 * 68);
        zi += zv[0]; zf += zv[1]; zg += zv[2]; zo += zv[3];
      }
      float ig = 1.f / (1.f + __expf(-zi));
      float fg = 1.f / (1.f + __expf(-zf));
      float gg = 2.f / (1.f + __expf(-2.f * zg)) - 1.f;
      float og = 1.f / (1.f + __expf(-zo));
      c_state = fg * c_state + ig * gg;
      float tc = 2.f / (1.f + __expf(-2.f * c_state)) - 1.f;
      float h  = og * tc;
      // publish packed h FIRST (critical path), then the nt out-store
      __bf16 hb16 = (__bf16)h;
      uint16_t hbits;
      __builtin_memcpy(&hbits, &hb16, 2);
      uint32_t mine = hbits;
      uint32_t partner = (uint32_t)__shfl_xor((int)mine, 1);   // ghc^1, same wave
      if ((ghc & 1) == 0) {
        uint32_t packed = mine | (partner << 16);
        __hip_atomic_store(&hd[(size_t)(t & 3) * 32768 + hdoff], packed,
                           __ATOMIC_RELAXED, __HIP_MEMORY_SCOPE_AGENT);
      }
      __builtin_nontemporal_store(h, &out[((size_t)m_g * kT + t) * kH + hcol]);
    }
    __syncthreads();                                 // B3: vmcnt(0) drain -> h at coherence pt

    // sentinel publish: this WG's 16 h-cols for step t are globally visible
    if (tid == 0)
      __hip_atomic_store(&sent[(((t & 7) * 4 + mq) * 4 + (cg >> 4)) * 16 + (cg & 15)], t,
                         __ATOMIC_RELAXED, __HIP_MEMORY_SCOPE_AGENT);

    // ---- tail: partials for step t+1 ----
    if (t < kT - 1) {
#pragma unroll
      for (int nt = 0; nt < 4; ++nt) acc[nt] = floatx4{0.f, 0.f, 0.f, 0.f};
      if (wave < 4) {                                // x-part of t+1: runs ahead
        const __bf16* asrc = xpk + (((size_t)(t + 1) * 4 + mq) * 32 + wave * 8) * 512
                           + (size_t)lane * 8;
#pragma unroll
        for (int cc = 0; cc < 8; ++cc) {
          bf16x8 a = __builtin_nontemporal_load((const bf16x8*)(asrc + (size_t)cc * 512));
#pragma unroll
          for (int nt = 0; nt < 4; ++nt)
            acc[nt] = __builtin_amdgcn_mfma_f32_16x16x32_bf16(a, breg[nt][cc], acc[nt], 0, 0, 0);
        }
      } else {                                       // h-part: light poll, one-shot load
        const int s = wave - 4;
        const int* sline = sent + (((t & 7) * 4 + mq) * 4 + s) * 16 + (lane & 15);
        int guard = 0;
        for (;;) {
          int v = __hip_atomic_load(sline, __ATOMIC_RELAXED, __HIP_MEMORY_SCOPE_AGENT);
          if (__all(v == t)) break;                  // all 16 producers published
          __builtin_amdgcn_s_sleep(2);
          if (++guard > (1 << 20)) break;            // fail loud, not hung
        }
        asm volatile("" ::: "memory");               // no hoisting data loads above poll
        const uint64_t* hb = (const uint64_t*)hd + (size_t)(t & 3) * 16384
                           + ((size_t)(mq * 128 + s * 32 + (lane >> 4)) * 16 + (lane & 15)) * 2;
        uint64_t w[8][2];
#pragma unroll
        for (int c = 0; c < 8; ++c) {
          w[c][0] = __hip_atomic_load(hb + (size_t)c * 128,     __ATOMIC_RELAXED,
                                      __HIP_MEMORY_SCOPE_AGENT);
          w[c][1] = __hip_atomic_load(hb + (size_t)c * 128 + 1, __ATOMIC_RELAXED,
                                      __HIP_MEMORY_SCOPE_AGENT);
        }
#pragma unroll
        for (int c = 0; c < 8; ++c) {
          union { uint64_t q[2]; bf16x8 v; } u;
          u.q[0] = w[c][0]; u.q[1] = w[c][1];
#pragma unroll
          for (int nt = 0; nt < 4; ++nt)
            acc[nt] = __builtin_amdgcn_mfma_f32_16x16x32_bf16(u.v, breg[nt][c], acc[nt], 0, 0, 0);
        }
      }
    }
  }
}

// ---------------------------------------------------------------------------
extern "C" void kernel_launch(void* const* d_in, const int* in_sizes, int n_in,
                              void* d_out, int out_size, void* d_ws, size_t ws_size,
                              hipStream_t stream) {
  const float* x  = (const float*)d_in[0];   // [64,512,1024]
  const float* Wx = (const float*)d_in[1];   // [1024,4096]
  const float* Wh = (const float*)d_in[2];   // [1024,4096]
  const float* b  = (const float*)d_in[3];   // [4096]
  float* out = (float*)d_out;

  char* ws = (char*)d_ws;
  int*      snt = (int*)ws;                                 // 8 KB sentinel lines
  uint32_t* hdb = (uint32_t*)(ws + ((size_t)1 << 16));      // 512 KB packed-h ring
  __bf16*   wpk = (__bf16*)(ws + ((size_t)1 << 20));        // 16 MB
  __bf16*   xpk = (__bf16*)(ws + ((size_t)17 << 20));       // 64 MB  (total 81 MB)
  (void)in_sizes; (void)n_in; (void)out_size; (void)ws_size;

  hipLaunchKernelGGL(pack_w, dim3(4096),  dim3(256), 0, stream, Wx, Wh, wpk);
  hipLaunchKernelGGL(pack_x, dim3(16384), dim3(256), 0, stream, x, xpk);
  hipLaunchKernelGGL(lstm_scan, dim3(256), dim3(512), 0, stream,
                     xpk, wpk, b, hdb, snt, out);
}